// Round 1
// baseline (512.678 us; speedup 1.0000x reference)
//
#include <hip/hip_runtime.h>
#include <hip/hip_bf16.h>

// PointSelfAttention: B=1024 molecules x K=64 pts, hidden=512, H=8 heads, D=64
// Pipeline: prep (w transpose->bf16, RBF bias table) -> k_attn (QKV+bias+softmax+PV,
// agg written to d_out) -> k_proj (out proj + residual + LayerNorm, in-place on d_out)

#define HID 512
#define TBL 2048
#define DMAX 12.0f

typedef __attribute__((ext_vector_type(4))) float f32x4;
typedef __attribute__((ext_vector_type(8))) short bhalf8;

__device__ __forceinline__ short f2bf(float f) {
    union { float f; unsigned u; } x; x.f = f;
    unsigned u = x.u;
    unsigned r = (u + 0x7FFFu + ((u >> 16) & 1u)) >> 16;  // RNE
    return (short)r;
}

// ---- prep: transpose weights to bf16 [cols][K] so MFMA B-frags read contiguous K ----
__global__ __launch_bounds__(256) void k_prep_w(const float* __restrict__ w_qkv,
                                                const float* __restrict__ w_out,
                                                short* __restrict__ wqT,
                                                short* __restrict__ woT) {
    __shared__ short tile[64][68];
    const int t = threadIdx.x;
    int bt = blockIdx.x;
    const float* src; short* dst; int sld, tk, tc;
    if (bt < 192) { src = w_qkv; dst = wqT; sld = 1536; tk = bt & 7; tc = bt >> 3; }
    else { int b2 = bt - 192; src = w_out; dst = woT; sld = 512; tk = b2 & 7; tc = b2 >> 3; }
#pragma unroll
    for (int p = 0; p < 4; ++p) {
        int s = t + 256 * p;
        int r = s >> 4, sg = s & 15;
        const float4 v = *(const float4*)(src + (tk * 64 + r) * sld + tc * 64 + sg * 4);
        tile[r][sg * 4 + 0] = f2bf(v.x);
        tile[r][sg * 4 + 1] = f2bf(v.y);
        tile[r][sg * 4 + 2] = f2bf(v.z);
        tile[r][sg * 4 + 3] = f2bf(v.w);
    }
    __syncthreads();
#pragma unroll
    for (int p = 0; p < 16; ++p) {
        int o = t + 256 * p;
        int c = o >> 6, k = o & 63;
        dst[(tc * 64 + c) * 512 + tk * 64 + k] = tile[k][c];
    }
}

// ---- prep: per-head bias(d) table: sum_r w_rbf[r,h]*exp(-(d-c_r)^2/w) + b_rbf[h] ----
__global__ __launch_bounds__(256) void k_prep_tbl(const float* __restrict__ centers,
                                                  const float* __restrict__ w_rbf,
                                                  const float* __restrict__ b_rbf,
                                                  float* __restrict__ tbl) {
    int idx = blockIdx.x * 256 + threadIdx.x;   // 8 heads * 2048
    int hh = idx >> 11, i = idx & (TBL - 1);
    float d = (float)i * (DMAX / (float)(TBL - 1));
    float s = b_rbf[hh];
    const float invw = 1.0f / 0.0625f;          // width = (8/32)^2
#pragma unroll 4
    for (int r = 0; r < 32; ++r) {
        float tt = d - centers[r];
        s += w_rbf[r * 8 + hh] * expf(-(tt * tt) * invw);
    }
    tbl[idx] = s;
}

// ---- kernel 1: per (molecule, head): QKV -> biased attention -> agg (into d_out) ----
__global__ __launch_bounds__(256) void k_attn(const float* __restrict__ h,
                                              const float* __restrict__ pos,
                                              const float* __restrict__ b_qkv,
                                              const short* __restrict__ wqT,
                                              const float* __restrict__ tbl,
                                              float* __restrict__ agg) {
    __shared__ __align__(16) short u0[64 * 72];    // h chunk, later q (scaled)
    __shared__ __align__(16) short u1[192 * 72];   // w chunk, later k | v^T | P
    __shared__ float s_px[64], s_py[64], s_pz[64];
    __shared__ float s_tbl[TBL];

    const int bid = blockIdx.x;
    const int mol = bid >> 3, head = bid & 7;
    const int t = threadIdx.x;
    const int wave = t >> 6, lane = t & 63;
    const int l16 = lane & 15, g = lane >> 4;
    const int rowbase = mol * 64;

    for (int i = t; i < TBL; i += 256) s_tbl[i] = tbl[head * TBL + i];
    if (t < 64) {
        s_px[t] = pos[(rowbase + t) * 3 + 0];
        s_py[t] = pos[(rowbase + t) * 3 + 1];
        s_pz[t] = pos[(rowbase + t) * 3 + 2];
    }

    f32x4 acc[12];
#pragma unroll
    for (int i = 0; i < 12; ++i) acc[i] = (f32x4){0.f, 0.f, 0.f, 0.f};

    // ---- QKV GEMM: C[64 rows x 192 cols(q|k|v)] over K=512 in chunks of 64 ----
    for (int kc = 0; kc < 8; ++kc) {
        const int kb = kc * 64;
#pragma unroll
        for (int p = 0; p < 4; ++p) {           // h chunk [64][64] fp32 -> bf16 LDS
            int s = t + 256 * p;
            int row = s >> 4, seg = s & 15;
            const float4 v = *(const float4*)(h + (rowbase + row) * HID + kb + seg * 4);
            short4 b4;
            b4.x = f2bf(v.x); b4.y = f2bf(v.y); b4.z = f2bf(v.z); b4.w = f2bf(v.w);
            *(short4*)(&u0[row * 72 + seg * 4]) = b4;
        }
#pragma unroll
        for (int p = 0; p < 6; ++p) {           // wT chunk [192 cols][64 k] bf16
            int s = t + 256 * p;
            int c = s >> 3, kq = s & 7;
            int sec = c >> 6, cc = c & 63;
            int gc = sec * 512 + head * 64 + cc;
            *(int4*)(&u1[c * 72 + kq * 8]) = *(const int4*)(wqT + gc * HID + kb + kq * 8);
        }
        __syncthreads();
        const int arow = wave * 16 + l16;
#pragma unroll
        for (int kk = 0; kk < 2; ++kk) {
            bhalf8 a = *(const bhalf8*)(&u0[arow * 72 + kk * 32 + g * 8]);
#pragma unroll
            for (int ct = 0; ct < 12; ++ct) {
                bhalf8 b = *(const bhalf8*)(&u1[(ct * 16 + l16) * 72 + kk * 32 + g * 8]);
                acc[ct] = __builtin_amdgcn_mfma_f32_16x16x32_bf16(a, b, acc[ct], 0, 0, 0);
            }
        }
        __syncthreads();
    }

    // ---- stage q (x scale, exact pow2) / k / v^T to LDS, + b_qkv ----
    const int r0 = wave * 16 + g * 4;
#pragma unroll
    for (int ct = 0; ct < 12; ++ct) {
        int c = ct * 16 + l16;
        int sec = c >> 6, cc = c & 63;          // sec uniform per ct (unrolled)
        float bv = b_qkv[sec * 512 + head * 64 + cc];
#pragma unroll
        for (int r = 0; r < 4; ++r) {
            float val = acc[ct][r] + bv;
            if (sec == 0)      u0[(r0 + r) * 72 + cc] = f2bf(val * 0.125f);
            else if (sec == 1) u1[(r0 + r) * 72 + cc] = f2bf(val);
            else               u1[4608 + cc * 72 + (r0 + r)] = f2bf(val);   // v^T
        }
    }
    __syncthreads();

    // ---- S = q_scaled . k^T  (wave owns rows wave*16..+15) ----
    f32x4 sacc[4];
#pragma unroll
    for (int i = 0; i < 4; ++i) sacc[i] = (f32x4){0.f, 0.f, 0.f, 0.f};
    const int srow = wave * 16 + l16;
#pragma unroll
    for (int kk = 0; kk < 2; ++kk) {
        bhalf8 a = *(const bhalf8*)(&u0[srow * 72 + kk * 32 + g * 8]);
#pragma unroll
        for (int ct = 0; ct < 4; ++ct) {
            bhalf8 b = *(const bhalf8*)(&u1[(ct * 16 + l16) * 72 + kk * 32 + g * 8]);
            sacc[ct] = __builtin_amdgcn_mfma_f32_16x16x32_bf16(a, b, sacc[ct], 0, 0, 0);
        }
    }

    // ---- + RBF bias via table lookup ----
    const float tscale = (float)(TBL - 1) / DMAX;
#pragma unroll
    for (int ct = 0; ct < 4; ++ct) {
        int col = ct * 16 + l16;
        float cx = s_px[col], cy = s_py[col], cz = s_pz[col];
#pragma unroll
        for (int r = 0; r < 4; ++r) {
            int row = r0 + r;
            float dx = s_px[row] - cx, dy = s_py[row] - cy, dz = s_pz[row] - cz;
            float dd = fmaf(dx, dx, fmaf(dy, dy, dz * dz));
            float dist = sqrtf(fmaxf(dd, 1e-12f));
            float u = fminf(dist, DMAX) * tscale;
            int i = (int)u; if (i > TBL - 2) i = TBL - 2;
            float fr = u - (float)i;
            float t0 = s_tbl[i];
            sacc[ct][r] += fmaf(fr, s_tbl[i + 1] - t0, t0);
        }
    }

    // ---- softmax over 64 cols (16-lane group x 4 tiles holds each row) ----
    float inv[4];
#pragma unroll
    for (int r = 0; r < 4; ++r) {
        float m = fmaxf(fmaxf(sacc[0][r], sacc[1][r]), fmaxf(sacc[2][r], sacc[3][r]));
#pragma unroll
        for (int off = 1; off < 16; off <<= 1) m = fmaxf(m, __shfl_xor(m, off, 64));
        float e0 = __expf(sacc[0][r] - m);
        float e1 = __expf(sacc[1][r] - m);
        float e2 = __expf(sacc[2][r] - m);
        float e3 = __expf(sacc[3][r] - m);
        float ssum = e0 + e1 + e2 + e3;
#pragma unroll
        for (int off = 1; off < 16; off <<= 1) ssum += __shfl_xor(ssum, off, 64);
        inv[r] = 1.0f / ssum;
        int pb = 9216 + (r0 + r) * 72 + l16;     // P staged bf16 (denom folded later)
        u1[pb + 0]  = f2bf(e0);
        u1[pb + 16] = f2bf(e1);
        u1[pb + 32] = f2bf(e2);
        u1[pb + 48] = f2bf(e3);
    }
    __syncthreads();

    // ---- agg = (P @ V) * inv ----
    f32x4 oacc[4];
#pragma unroll
    for (int i = 0; i < 4; ++i) oacc[i] = (f32x4){0.f, 0.f, 0.f, 0.f};
    const int prow = wave * 16 + l16;
#pragma unroll
    for (int kk = 0; kk < 2; ++kk) {
        bhalf8 a = *(const bhalf8*)(&u1[9216 + prow * 72 + kk * 32 + g * 8]);
#pragma unroll
        for (int ct = 0; ct < 4; ++ct) {
            bhalf8 b = *(const bhalf8*)(&u1[4608 + (ct * 16 + l16) * 72 + kk * 32 + g * 8]);
            oacc[ct] = __builtin_amdgcn_mfma_f32_16x16x32_bf16(a, b, oacc[ct], 0, 0, 0);
        }
    }
#pragma unroll
    for (int ct = 0; ct < 4; ++ct) {
        int col = head * 64 + ct * 16 + l16;
#pragma unroll
        for (int r = 0; r < 4; ++r) {
            agg[(rowbase + r0 + r) * HID + col] = oacc[ct][r] * inv[r];
        }
    }
}

// ---- kernel 2: out = agg @ w_out + b_out + h, then LayerNorm (in-place on d_out) ----
__global__ __launch_bounds__(256) void k_proj(const float* __restrict__ aggIn,
                                              const float* __restrict__ h,
                                              const short* __restrict__ woT,
                                              const float* __restrict__ b_out,
                                              const float* __restrict__ gamma,
                                              const float* __restrict__ beta,
                                              float* __restrict__ out) {
    __shared__ __align__(16) short m0[64 * 40];    // agg chunk [64][32] bf16
    __shared__ __align__(16) short m1[512 * 40];   // w_out^T chunk [512][32] bf16
    const int mol = blockIdx.x;
    const int t = threadIdx.x;
    const int wave = t >> 6, lane = t & 63;
    const int l16 = lane & 15, g = lane >> 4;
    const int rowbase = mol * 64;

    f32x4 acc[32];
#pragma unroll
    for (int i = 0; i < 32; ++i) acc[i] = (f32x4){0.f, 0.f, 0.f, 0.f};

    for (int kc = 0; kc < 16; ++kc) {
        const int kb = kc * 32;
#pragma unroll
        for (int p = 0; p < 2; ++p) {
            int s = t + 256 * p;
            int row = s >> 3, seg = s & 7;
            const float4 v = *(const float4*)(aggIn + (rowbase + row) * HID + kb + seg * 4);
            short4 b4;
            b4.x = f2bf(v.x); b4.y = f2bf(v.y); b4.z = f2bf(v.z); b4.w = f2bf(v.w);
            *(short4*)(&m0[row * 40 + seg * 4]) = b4;
        }
#pragma unroll
        for (int p = 0; p < 8; ++p) {
            int s = t + 256 * p;
            int c = s >> 2, kq = s & 3;
            *(int4*)(&m1[c * 40 + kq * 8]) = *(const int4*)(woT + c * HID + kb + kq * 8);
        }
        __syncthreads();
        const int arow = wave * 16 + l16;
        bhalf8 a = *(const bhalf8*)(&m0[arow * 40 + g * 8]);
#pragma unroll
        for (int ct = 0; ct < 32; ++ct) {
            bhalf8 b = *(const bhalf8*)(&m1[(ct * 16 + l16) * 40 + g * 8]);
            acc[ct] = __builtin_amdgcn_mfma_f32_16x16x32_bf16(a, b, acc[ct], 0, 0, 0);
        }
        __syncthreads();
    }

    // ---- + b_out + residual, LayerNorm across 512 (16 lanes x 32 tiles) ----
    const int r0 = wave * 16 + g * 4;
    float sum[4] = {0.f, 0.f, 0.f, 0.f}, sq[4] = {0.f, 0.f, 0.f, 0.f};
#pragma unroll
    for (int ct = 0; ct < 32; ++ct) {
        int col = ct * 16 + l16;
        float bo = b_out[col];
#pragma unroll
        for (int r = 0; r < 4; ++r) {
            float v = acc[ct][r] + bo + h[(rowbase + r0 + r) * HID + col];
            acc[ct][r] = v;
            sum[r] += v;
            sq[r] = fmaf(v, v, sq[r]);
        }
    }
#pragma unroll
    for (int r = 0; r < 4; ++r) {
#pragma unroll
        for (int off = 1; off < 16; off <<= 1) {
            sum[r] += __shfl_xor(sum[r], off, 64);
            sq[r]  += __shfl_xor(sq[r], off, 64);
        }
    }
    float mean[4], rstd[4];
#pragma unroll
    for (int r = 0; r < 4; ++r) {
        mean[r] = sum[r] * (1.0f / 512.0f);
        float var = sq[r] * (1.0f / 512.0f) - mean[r] * mean[r];
        rstd[r] = rsqrtf(var + 1e-5f);
    }
#pragma unroll
    for (int ct = 0; ct < 32; ++ct) {
        int col = ct * 16 + l16;
        float ga = gamma[col], be = beta[col];
#pragma unroll
        for (int r = 0; r < 4; ++r) {
            out[(rowbase + r0 + r) * HID + col] =
                fmaf((acc[ct][r] - mean[r]) * rstd[r], ga, be);
        }
    }
}

extern "C" void kernel_launch(void* const* d_in, const int* in_sizes, int n_in,
                              void* d_out, int out_size, void* d_ws, size_t ws_size,
                              hipStream_t stream) {
    (void)in_sizes; (void)n_in; (void)out_size; (void)ws_size;
    const float* h       = (const float*)d_in[0];
    const float* pos     = (const float*)d_in[1];
    // d_in[2] = batch (unused: equal-size contiguous molecules)
    const float* centers = (const float*)d_in[3];
    const float* w_rbf   = (const float*)d_in[4];
    const float* b_rbf   = (const float*)d_in[5];
    const float* w_qkv   = (const float*)d_in[6];
    const float* b_qkv   = (const float*)d_in[7];
    const float* w_out   = (const float*)d_in[8];
    const float* b_out   = (const float*)d_in[9];
    const float* gamma   = (const float*)d_in[10];
    const float* beta    = (const float*)d_in[11];
    float* out = (float*)d_out;

    char* ws = (char*)d_ws;
    short* wqT = (short*)ws;                         // [1536][512] bf16 = 1.5 MB
    short* woT = (short*)(ws + 1572864);             // [512][512]  bf16 = 0.5 MB
    float* tbl = (float*)(ws + 2097152);             // [8][2048]   f32  = 64 KB

    k_prep_w<<<256, 256, 0, stream>>>(w_qkv, w_out, wqT, woT);
    k_prep_tbl<<<64, 256, 0, stream>>>(centers, w_rbf, b_rbf, tbl);
    k_attn<<<8192, 256, 0, stream>>>(h, pos, b_qkv, wqT, tbl, out);
    k_proj<<<1024, 256, 0, stream>>>(out, h, woT, b_out, gamma, beta, out);
}